// Round 6
// baseline (1531.365 us; speedup 1.0000x reference)
//
#include <hip/hip_runtime.h>
#include <math.h>

// B=32, R=16384, C=16, IC=16, OC=16, 3 routing iterations.
// x: (B,C,IC) fp32 [8192]; W: (R,C,OC,IC) fp32 [67108864 = 256 MB]; out: (B,C,OC) fp32.
//
// Algebra 1: b after iter2 = <u,v1>, after iter3 = <u,v1+v2> -> no logit array.
// Algebra 2: iter-1 needs S[b,c,o] = sum_r u[b,c,r,o]; computed by the SAME
// streaming kernel with uniform weights (MODE 0) -> no separate W-sum pass
// (R4/R5's k_wsum+k_wred_v1 chain was ~330 us, as large as both routes).
//
// k_route history: R1/R4 (8w, bl=4, o-full, 128KB dbuf) = 221/170 us: ~163 live
// regs vs 128 arch-VGPRs -> AGPR shuttling + 2 waves/SIMD latency wall.
// R5 (16w, bl=2): compiler chose 64 VGPRs (2-blocks/CU heuristic; LDS pins 1)
// -> 400 MB scratch spills. R2/R3 restructures also spill-bound.
// This round: 32-row chunks (2x32KB LDS = 64KB -> 2 blocks/CU, 4 waves/SIMD),
// lane split on o-halves (rl=lane&31, oh=lane>>5): u[4][8]+accE[4][8]=64 regs,
// x in SGPR, v-half in VGPR -> live ~120 fits the 128 budget pinned by
// amdgpu_waves_per_eu(4,4) (exact attr, not launch_bounds heuristics).

#define RT 16384

// dot of 4 float4 (VGPR) against 16 scalars (SGPR) -- v_fmac v,s,v is legal.
#define DOT16S(w0,w1,w2,w3,xs) \
  (w0.x*xs[0] + w0.y*xs[1] + w0.z*xs[2] + w0.w*xs[3] + \
   w1.x*xs[4] + w1.y*xs[5] + w1.z*xs[6] + w1.w*xs[7] + \
   w2.x*xs[8] + w2.y*xs[9] + w2.z*xs[10] + w2.w*xs[11] + \
   w3.x*xs[12] + w3.y*xs[13] + w3.z*xs[14] + w3.w*xs[15])

// async global->LDS, 16 B per lane. LDS dest = wave-uniform base + lane*16.
__device__ __forceinline__ void gload_lds16(const void* g, void* l) {
  __builtin_amdgcn_global_load_lds(
      (const __attribute__((address_space(1))) unsigned int*)g,
      (__attribute__((address_space(3))) unsigned int*)l, 16, 0, 0);
}

__device__ __forceinline__ float rfl(float v) {
  return __uint_as_float(__builtin_amdgcn_readfirstlane(__float_as_uint(v)));
}

// ---------------------------------------------------------------------------
// k_v1: v1 = squash(S / R), S = E1[b,c,o] (sum over r of u, from MODE-0 pass)
// ---------------------------------------------------------------------------
__global__ __launch_bounds__(256) void k_v1(const float* __restrict__ E1,
                                            float* __restrict__ v1) {
    int t = blockIdx.x * 256 + threadIdx.x;        // 0..8191
    float s = E1[t] * (1.0f / 16384.0f);
    float ns = s * s;
    #pragma unroll
    for (int d = 1; d < 16; d <<= 1) ns += __shfl_xor(ns, d);
    v1[t] = s * (sqrtf(ns) / (1.0f + ns));
}

// k_vsum: v2 = squash(E/Z); vsum = v1 + v2
__global__ __launch_bounds__(256) void k_vsum(const float* __restrict__ E,
                                              const float* __restrict__ Z,
                                              const float* __restrict__ v1,
                                              float* __restrict__ vsum) {
    int t = blockIdx.x * 256 + threadIdx.x;
    float s = E[t] / Z[t >> 4];
    float ns = s * s;
    #pragma unroll
    for (int d = 1; d < 16; d <<= 1) ns += __shfl_xor(ns, d);
    vsum[t] = v1[t] + s * (sqrtf(ns) / (1.0f + ns));
}

// k_vout: final v = squash(E/Z) -> out
__global__ __launch_bounds__(256) void k_vout(const float* __restrict__ E,
                                              const float* __restrict__ Z,
                                              float* __restrict__ dst) {
    int t = blockIdx.x * 256 + threadIdx.x;
    float s = E[t] / Z[t >> 4];
    float ns = s * s;
    #pragma unroll
    for (int d = 1; d < 16; d <<= 1) ns += __shfl_xor(ns, d);
    dst[t] = s * (sqrtf(ns) / (1.0f + ns));
}

// ---------------------------------------------------------------------------
// k_route<MODE,REV>: one W-streaming pass.
//   u[o] = sum_i W[r,c,o,i]*x[b,c,i]
//   MODE 0: E[b,c,o] += u[o]                        (uniform routing, iter 1)
//   MODE 1: e = exp(<u,v>); E += e*u; Z += e        (iters 2,3)
// Block 512 = 8 waves; wave wv owns b in {4wv..4wv+3}.
// Lane: rl = lane&31 = row in 32-row chunk; oh = lane>>5 = o-half.
// 8 chunks per 256-row tile; 2x32KB LDS double buffer, prefetch-then-compute.
// LDS float4-XOR swizzle: slot rl*64+l holds row rl's float4 (l^rl); per
// wave-instr the 8-lane-group bank-quads ((oo*4+q)^rl)&7 are all distinct ->
// conflict-free b128 at the ~12cyc floor. Staging source is pre-swizzled,
// LDS dest linear (both-sides-or-neither rule for global_load_lds).
// Lv cross-half: Lv = part + shfl_xor(part, 32); exp duplicated in halves.
// REV: reverse r walk for L3 tail reuse between consecutive passes.
// ---------------------------------------------------------------------------
template <int MODE, int REV>
__global__ __launch_bounds__(512)
__attribute__((amdgpu_waves_per_eu(4, 4)))
void k_route(const float* __restrict__ W,
             const float* __restrict__ x,
             const float* __restrict__ v,
             float* __restrict__ E,
             float* __restrict__ Z) {
    __shared__ float4 Wl[2][32 * 64];              // 2 x 32 KB double buffer
    const int c = blockIdx.y;
    const int bx = REV ? (63 - (int)blockIdx.x) : (int)blockIdx.x;
    const int r0 = bx * 256;
    const int tid = threadIdx.x;
    const int wv = __builtin_amdgcn_readfirstlane(tid >> 6);   // [0,8)
    const int lane = tid & 63;
    const int rl = lane & 31;                      // row within chunk
    const int oh = lane >> 5;                      // o-half: o = oh*8+oo

    const float4* W4c = (const float4*)W + c * 64; // + r*1024 + j

    // x rows for this wave's 4 b's -> SGPRs (wave-uniform)
    float xs[4][16];
    #pragma unroll
    for (int bl = 0; bl < 4; ++bl) {
        const float* xb = x + ((wv * 4 + bl) * 16 + c) * 16;
        #pragma unroll
        for (int i = 0; i < 16; ++i) xs[bl][i] = rfl(xb[i]);
    }
    // v half-rows for this lane's o-half -> VGPRs (8 per bl)
    float vsv[4][8];
    if (MODE) {
        #pragma unroll
        for (int bl = 0; bl < 4; ++bl) {
            const float* vb = v + ((wv * 4 + bl) * 16 + c) * 16 + oh * 8;
            #pragma unroll
            for (int oo = 0; oo < 8; ++oo) vsv[bl][oo] = vb[oo];
        }
    }

    float accE[4][8];
    float accZ[4] = {0.f, 0.f, 0.f, 0.f};
    #pragma unroll
    for (int bl = 0; bl < 4; ++bl)
        #pragma unroll
        for (int oo = 0; oo < 8; ++oo) accE[bl][oo] = 0.f;

    // stage chunk 0: wave wv stages rows {k*8+wv}; lane l -> slot rl_s*64+l,
    // global source pre-swizzled: float4 (l ^ rl_s) of the row.
    #pragma unroll
    for (int k = 0; k < 4; ++k) {
        int rs = k * 8 + wv;
        gload_lds16(W4c + (size_t)(r0 + rs) * 1024 + (lane ^ rs), &Wl[0][rs * 64]);
    }
    __syncthreads();                               // drains vmcnt(0)

    #pragma unroll
    for (int ch = 0; ch < 8; ++ch) {
        if (ch < 7) {                              // issue next chunk's loads first
            #pragma unroll
            for (int k = 0; k < 4; ++k) {
                int rs = k * 8 + wv;
                gload_lds16(W4c + (size_t)(r0 + (ch + 1) * 32 + rs) * 1024 + (lane ^ rs),
                            &Wl[(ch + 1) & 1][rs * 64]);
            }
        }
        const float4* Wb = Wl[ch & 1];

        float u[4][8];
        #pragma unroll
        for (int oo = 0; oo < 8; ++oo) {
            int o4 = (oh * 8 + oo) * 4;
            float4 w0 = Wb[rl * 64 + ((o4 + 0) ^ rl)];
            float4 w1 = Wb[rl * 64 + ((o4 + 1) ^ rl)];
            float4 w2 = Wb[rl * 64 + ((o4 + 2) ^ rl)];
            float4 w3 = Wb[rl * 64 + ((o4 + 3) ^ rl)];
            #pragma unroll
            for (int bl = 0; bl < 4; ++bl)
                u[bl][oo] = DOT16S(w0, w1, w2, w3, xs[bl]);
        }

        #pragma unroll
        for (int bl = 0; bl < 4; ++bl) {
            if (MODE) {
                float part = 0.f;
                #pragma unroll
                for (int oo = 0; oo < 8; ++oo) part += u[bl][oo] * vsv[bl][oo];
                float Lv = part + __shfl_xor(part, 32);    // join o-halves
                float e = __expf(Lv);
                accZ[bl] += e;
                #pragma unroll
                for (int oo = 0; oo < 8; ++oo) accE[bl][oo] += e * u[bl][oo];
            } else {
                #pragma unroll
                for (int oo = 0; oo < 8; ++oo) accE[bl][oo] += u[bl][oo];
            }
        }
        __syncthreads();   // barrier + vmcnt(0) drain of loads issued pre-compute
    }

    // Reduce accE over the 32 rows (butterfly within each 32-lane half; d<32
    // never crosses halves, so each half reduces its own o-range).
    float va = 0.f;
    #pragma unroll
    for (int bl = 0; bl < 4; ++bl) {
        #pragma unroll
        for (int oo = 0; oo < 8; ++oo) {
            float t = accE[bl][oo];
            #pragma unroll
            for (int d = 1; d < 32; d <<= 1) t += __shfl_xor(t, d);
            if (rl == bl * 8 + oo) va = t;
        }
    }
    {
        int b = wv * 4 + (rl >> 3);
        int o = oh * 8 + (rl & 7);
        atomicAdd(&E[b * 256 + c * 16 + o], va);
    }
    if (MODE) {
        float vz = 0.f;
        #pragma unroll
        for (int bl = 0; bl < 4; ++bl) {
            float t = accZ[bl];
            #pragma unroll
            for (int d = 1; d < 32; d <<= 1) t += __shfl_xor(t, d);
            if (lane == bl) vz = t;                // lanes 0-3: lower half only
        }
        if (lane < 4) atomicAdd(&Z[(wv * 4 + lane) * 16 + c], vz);
    }
}

// ---------------------------------------------------------------------------
// launch
// ---------------------------------------------------------------------------
extern "C" void kernel_launch(void* const* d_in, const int* in_sizes, int n_in,
                              void* d_out, int out_size, void* d_ws, size_t ws_size,
                              hipStream_t stream) {
    const float* x = (const float*)d_in[0];        // 8192 floats
    const float* W = (const float*)d_in[1];        // 67108864 floats (256 MB)
    float* out = (float*)d_out;                    // 8192 floats
    float* ws = (float*)d_ws;

    float* E1   = ws + 0;          // 8192  (S = sum_r u)
    float* E2   = ws + 8192;       // 8192
    float* Z2   = ws + 16384;      // 512
    float* E3   = ws + 16896;      // 8192
    float* Z3   = ws + 25088;      // 512   (zeroed region ends at 25600)
    float* v1   = ws + 25600;      // 8192
    float* vsum = ws + 33792;      // 8192

    hipMemsetAsync(ws, 0, 25600 * sizeof(float), stream);

    // iter 1: S = sum_r u (uniform routing), W pass 1 (forward r)
    k_route<0, 0><<<dim3(64, 16), 512, 0, stream>>>(W, x, v1, E1, Z2);
    k_v1<<<32, 256, 0, stream>>>(E1, v1);          // v1 = squash(S/R)

    // iter 2: logits = <u, v1>, W pass 2 (reverse r for L3 tail reuse)
    k_route<1, 1><<<dim3(64, 16), 512, 0, stream>>>(W, x, v1, E2, Z2);
    k_vsum<<<32, 256, 0, stream>>>(E2, Z2, v1, vsum);  // vsum = v1 + squash(E2/Z2)

    // iter 3: logits = <u, v1+v2>, W pass 3 (forward r)
    k_route<1, 0><<<dim3(64, 16), 512, 0, stream>>>(W, x, vsum, E3, Z3);
    k_vout<<<32, 256, 0, stream>>>(E3, Z3, out);
}

// Round 7
// 656.149 us; speedup vs baseline: 2.3339x; 2.3339x over previous
//
#include <hip/hip_runtime.h>
#include <math.h>

// B=32, R=16384, C=16, IC=16, OC=16, 3 routing iterations.
// x: (B,C,IC) fp32 [8192]; W: (R,C,OC,IC) fp32 [67108864 = 256 MB]; out: (B,C,OC) fp32.
//
// Algebra 1: b after iter2 = <u,v1>, after iter3 = <u,v1+v2> -> no logit array.
// Algebra 2: iter-1 is the same streaming kernel with uniform weights (MODE 0).
//
// Allocator law (measured R4/R5/R6): arch-VGPR granted = (512/waves_req)/2 --
// the unified file is split half VGPR / half AGPR. Requesting 4 waves/EU gives
// 64 arch VGPRs. So the kernel is DESIGNED for a <=~56-reg live set:
//   16 waves x b-pair  (b covered inside one block -> W still streamed once)
//   lane = (rl = row 0..31) x (oh = o-half 0/1)
//   u[2][8]=16 + accE[2][8]=16 + w-frags=16 + addr ~8  ~= 56 VGPR
//   x -> SGPR (readfirstlane); v -> 2 KB LDS broadcast table (NOT registers)
// LDS 66 KB -> 2 blocks/CU -> 8 waves/SIMD (R4 had 2: its latency wall).
// Floors per pass: HBM 41 us, LDS-read 27 us (16x amplification), VALU 31 us.

#define RT 16384

// dot of 4 float4 (VGPR) against 16 scalars (SGPR) -- v_fmac v,s,v is legal.
#define DOT16S(w0,w1,w2,w3,xs) \
  (w0.x*xs[0] + w0.y*xs[1] + w0.z*xs[2] + w0.w*xs[3] + \
   w1.x*xs[4] + w1.y*xs[5] + w1.z*xs[6] + w1.w*xs[7] + \
   w2.x*xs[8] + w2.y*xs[9] + w2.z*xs[10] + w2.w*xs[11] + \
   w3.x*xs[12] + w3.y*xs[13] + w3.z*xs[14] + w3.w*xs[15])

// async global->LDS, 16 B per lane. LDS dest = wave-uniform base + lane*16.
__device__ __forceinline__ void gload_lds16(const void* g, void* l) {
  __builtin_amdgcn_global_load_lds(
      (const __attribute__((address_space(1))) unsigned int*)g,
      (__attribute__((address_space(3))) unsigned int*)l, 16, 0, 0);
}

__device__ __forceinline__ float rfl(float v) {
  return __uint_as_float(__builtin_amdgcn_readfirstlane(__float_as_uint(v)));
}

// ---------------------------------------------------------------------------
// k_v1: v1 = squash(S / R), S = E1[b,c,o] (sum over r of u, from MODE-0 pass)
// ---------------------------------------------------------------------------
__global__ __launch_bounds__(256) void k_v1(const float* __restrict__ E1,
                                            float* __restrict__ v1) {
    int t = blockIdx.x * 256 + threadIdx.x;        // 0..8191
    float s = E1[t] * (1.0f / 16384.0f);
    float ns = s * s;
    #pragma unroll
    for (int d = 1; d < 16; d <<= 1) ns += __shfl_xor(ns, d);
    v1[t] = s * (sqrtf(ns) / (1.0f + ns));
}

// k_vsum: v2 = squash(E/Z); vsum = v1 + v2
__global__ __launch_bounds__(256) void k_vsum(const float* __restrict__ E,
                                              const float* __restrict__ Z,
                                              const float* __restrict__ v1,
                                              float* __restrict__ vsum) {
    int t = blockIdx.x * 256 + threadIdx.x;
    float s = E[t] / Z[t >> 4];
    float ns = s * s;
    #pragma unroll
    for (int d = 1; d < 16; d <<= 1) ns += __shfl_xor(ns, d);
    vsum[t] = v1[t] + s * (sqrtf(ns) / (1.0f + ns));
}

// k_vout: final v = squash(E/Z) -> out
__global__ __launch_bounds__(256) void k_vout(const float* __restrict__ E,
                                              const float* __restrict__ Z,
                                              float* __restrict__ dst) {
    int t = blockIdx.x * 256 + threadIdx.x;
    float s = E[t] / Z[t >> 4];
    float ns = s * s;
    #pragma unroll
    for (int d = 1; d < 16; d <<= 1) ns += __shfl_xor(ns, d);
    dst[t] = s * (sqrtf(ns) / (1.0f + ns));
}

// ---------------------------------------------------------------------------
// k_route<MODE,REV>: one W-streaming pass.
//   u[o] = sum_i W[r,c,o,i]*x[b,c,i]
//   MODE 0: E[b,c,o] += u[o]                        (uniform routing, iter 1)
//   MODE 1: e = exp(<u,v>); E += e*u; Z += e        (iters 2,3)
// Block 1024 = 16 waves; wave wv owns b in {2wv, 2wv+1}.
// Lane: rl = lane&31 = row in 32-row chunk; oh = lane>>5 = o-half.
// 8 chunks per 256-row tile; 2x32KB LDS double buffer, prefetch-then-compute.
// LDS float4-XOR swizzle: slot rs*64+l holds row rs's float4 (l^rs); reads
// Wb[rl*64 + ((o4+q)^rl)] put 8 lanes on each 4-bank group = 2 words/bank/
// phase = free 2-way aliasing -> b128 at the 4-clk BW floor.
// Staging source pre-swizzled, LDS dest linear (both-sides-or-neither rule).
// Lv cross-half: Lv = part + shfl_xor(part, 32); exp duplicated in halves.
// v is read from the Vl LDS table at USE time (broadcast; 2 addrs/wave-instr)
// to keep it out of the register file.
// ---------------------------------------------------------------------------
template <int MODE, int REV>
__global__ __launch_bounds__(1024, 4)
void k_route(const float* __restrict__ W,
             const float* __restrict__ x,
             const float* __restrict__ v,
             float* __restrict__ E,
             float* __restrict__ Z) {
    __shared__ float4 Wl[2][32 * 64];              // 2 x 32 KB double buffer
    __shared__ float Vl[512];                      // v broadcast table (2 KB)
    const int c = blockIdx.y;
    const int bx = REV ? (63 - (int)blockIdx.x) : (int)blockIdx.x;
    const int r0 = bx * 256;
    const int tid = threadIdx.x;
    const int wv = __builtin_amdgcn_readfirstlane(tid >> 6);   // [0,16)
    const int lane = tid & 63;
    const int rl = lane & 31;                      // row within chunk
    const int oh = lane >> 5;                      // o-half: o = oh*8+oo

    const float4* W4c = (const float4*)W + c * 64; // + r*1024 + j

    if (MODE && tid < 512)                         // Vl[b*16+o] = v[b,c,o]
        Vl[tid] = v[(tid >> 4) * 256 + c * 16 + (tid & 15)];

    // x rows for this wave's 2 b's -> SGPRs (wave-uniform)
    float xs[2][16];
    #pragma unroll
    for (int bl = 0; bl < 2; ++bl) {
        const float* xb = x + ((wv * 2 + bl) * 16 + c) * 16;
        #pragma unroll
        for (int i = 0; i < 16; ++i) xs[bl][i] = rfl(xb[i]);
    }

    float accE[2][8];
    float accZ[2] = {0.f, 0.f};
    #pragma unroll
    for (int bl = 0; bl < 2; ++bl)
        #pragma unroll
        for (int oo = 0; oo < 8; ++oo) accE[bl][oo] = 0.f;

    // stage chunk 0: wave wv stages rows {2wv, 2wv+1}; lane l -> slot rs*64+l,
    // global source pre-swizzled: float4 (l ^ rs) of the row.
    #pragma unroll
    for (int k = 0; k < 2; ++k) {
        int rs = wv * 2 + k;
        gload_lds16(W4c + (size_t)(r0 + rs) * 1024 + (lane ^ rs), &Wl[0][rs * 64]);
    }
    __syncthreads();                               // drains vmcnt(0) + Vl ready

    #pragma unroll
    for (int ch = 0; ch < 8; ++ch) {
        if (ch < 7) {                              // issue next chunk's loads first
            #pragma unroll
            for (int k = 0; k < 2; ++k) {
                int rs = wv * 2 + k;
                gload_lds16(W4c + (size_t)(r0 + (ch + 1) * 32 + rs) * 1024 + (lane ^ rs),
                            &Wl[(ch + 1) & 1][rs * 64]);
            }
        }
        const float4* Wb = Wl[ch & 1];

        float u[2][8];
        #pragma unroll
        for (int oo = 0; oo < 8; ++oo) {
            int o4 = (oh * 8 + oo) * 4;
            float4 w0 = Wb[rl * 64 + ((o4 + 0) ^ rl)];
            float4 w1 = Wb[rl * 64 + ((o4 + 1) ^ rl)];
            float4 w2 = Wb[rl * 64 + ((o4 + 2) ^ rl)];
            float4 w3 = Wb[rl * 64 + ((o4 + 3) ^ rl)];
            #pragma unroll
            for (int bl = 0; bl < 2; ++bl)
                u[bl][oo] = DOT16S(w0, w1, w2, w3, xs[bl]);
        }

        #pragma unroll
        for (int bl = 0; bl < 2; ++bl) {
            if (MODE) {
                const float* vb = &Vl[(wv * 2 + bl) * 16 + oh * 8];
                float part = 0.f;
                #pragma unroll
                for (int oo = 0; oo < 8; ++oo) part += u[bl][oo] * vb[oo];
                float Lv = part + __shfl_xor(part, 32);    // join o-halves
                float e = __expf(Lv);
                accZ[bl] += e;
                #pragma unroll
                for (int oo = 0; oo < 8; ++oo) accE[bl][oo] += e * u[bl][oo];
            } else {
                #pragma unroll
                for (int oo = 0; oo < 8; ++oo) accE[bl][oo] += u[bl][oo];
            }
        }
        __syncthreads();   // barrier + vmcnt(0) drain of loads issued pre-compute
    }

    // Reduce accE over the 32 rows (butterfly within each 32-lane half; d<32
    // never crosses halves, so each half reduces its own o-range).
    float va = 0.f;
    #pragma unroll
    for (int bl = 0; bl < 2; ++bl) {
        #pragma unroll
        for (int oo = 0; oo < 8; ++oo) {
            float t = accE[bl][oo];
            #pragma unroll
            for (int d = 1; d < 32; d <<= 1) t += __shfl_xor(t, d);
            if (rl == bl * 8 + oo) va = t;
        }
    }
    if (rl < 16) {
        int b = wv * 2 + (rl >> 3);
        int o = oh * 8 + (rl & 7);
        atomicAdd(&E[b * 256 + c * 16 + o], va);
    }
    if (MODE) {
        float vz = 0.f;
        #pragma unroll
        for (int bl = 0; bl < 2; ++bl) {
            float t = accZ[bl];
            #pragma unroll
            for (int d = 1; d < 32; d <<= 1) t += __shfl_xor(t, d);
            if (lane == bl) vz = t;                // lanes 0,1: lower half only
        }
        if (lane < 2) atomicAdd(&Z[(wv * 2 + lane) * 16 + c], vz);
    }
}

// ---------------------------------------------------------------------------
// launch
// ---------------------------------------------------------------------------
extern "C" void kernel_launch(void* const* d_in, const int* in_sizes, int n_in,
                              void* d_out, int out_size, void* d_ws, size_t ws_size,
                              hipStream_t stream) {
    const float* x = (const float*)d_in[0];        // 8192 floats
    const float* W = (const float*)d_in[1];        // 67108864 floats (256 MB)
    float* out = (float*)d_out;                    // 8192 floats
    float* ws = (float*)d_ws;

    float* E1   = ws + 0;          // 8192  (S = sum_r u)
    float* E2   = ws + 8192;       // 8192
    float* Z2   = ws + 16384;      // 512
    float* E3   = ws + 16896;      // 8192
    float* Z3   = ws + 25088;      // 512   (zeroed region ends at 25600)
    float* v1   = ws + 25600;      // 8192
    float* vsum = ws + 33792;      // 8192

    hipMemsetAsync(ws, 0, 25600 * sizeof(float), stream);

    // iter 1: S = sum_r u (uniform routing), W pass 1 (forward r)
    k_route<0, 0><<<dim3(64, 16), 1024, 0, stream>>>(W, x, v1, E1, Z2);
    k_v1<<<32, 256, 0, stream>>>(E1, v1);          // v1 = squash(S/R)

    // iter 2: logits = <u, v1>, W pass 2 (reverse r for L3 tail reuse)
    k_route<1, 1><<<dim3(64, 16), 1024, 0, stream>>>(W, x, v1, E2, Z2);
    k_vsum<<<32, 256, 0, stream>>>(E2, Z2, v1, vsum);  // vsum = v1 + squash(E2/Z2)

    // iter 3: logits = <u, v1+v2>, W pass 3 (forward r)
    k_route<1, 0><<<dim3(64, 16), 1024, 0, stream>>>(W, x, vsum, E3, Z3);
    k_vout<<<32, 256, 0, stream>>>(E3, Z3, out);
}